// Round 1
// baseline (166.991 us; speedup 1.0000x reference)
//
#include <hip/hip_runtime.h>
#include <math.h>

// Problem constants (B=16, H=W=1024, WIDTH=3, SIGMA=1, BLUR_SIGMA=1.5, EPS=1e-8)
#define BB    16
#define HH    1024
#define WW    1024
#define EPSF  1e-8f
#define RAD   4                  // blur radius: int(3 * 1.5)
#define MARG  24.f               // support margin: sigmoid(3-24) ~ 7.6e-10
#define WMAX  256                // max dep-chunk width handled per LDS pass
#define FW    (WMAX + 16)        // 272: draw row width (compile-time const for cheap div)

struct BlurK { float k[9]; };

__device__ __forceinline__ float sigf(float z) {
    z = fmaxf(fminf(z, 40.f), -40.f);
    return 1.f / (1.f + __expf(-z));
}

struct Geom { float p0x, p0y, p1x, p1y, L, ux, uy; };

__device__ __forceinline__ Geom load_geom(const float* as, const float* ae, int b) {
    Geom g;
    g.p0x = as[3 * b];  g.p0y = as[3 * b + 1];
    g.p1x = ae[3 * b];  g.p1y = ae[3 * b + 1];
    float dx = g.p1x - g.p0x, dy = g.p1y - g.p0y;
    g.L  = sqrtf(dx * dx + dy * dy + EPSF);
    g.ux = dx / g.L;  g.uy = dy / g.L;
    return g;
}

__device__ __forceinline__ float sweptf(const Geom& g, float x, float y) {
    float rx = x - g.p0x, ry = y - g.p0y;
    float t  = fminf(fmaxf(rx * g.ux + ry * g.uy, 0.f), g.L);
    float dx = rx - t * g.ux, dy = ry - t * g.uy;
    float dist = sqrtf(dx * dx + dy * dy + EPSF);
    return sigf(3.f - dist);
}

__device__ __forceinline__ void slat(const Geom& g, float x, float y, float& s, float& lat) {
    float qx = x - g.p1x, qy = y - g.p1y;
    s = qx * g.ux + qy * g.uy;
    float r = qx * (-g.uy) + qy * g.ux;   // n = (-uy, ux)
    lat = sigf(3.f - fabsf(r));
}

__device__ __forceinline__ void capsule_bbox(const Geom& g, float m,
                                             int& x0, int& x1, int& y0, int& y1) {
    x0 = max(0, (int)floorf(fminf(g.p0x, g.p1x) - m));
    x1 = min(WW - 1, (int)ceilf(fmaxf(g.p0x, g.p1x) + m));
    y0 = max(0, (int)floorf(fminf(g.p0y, g.p1y) - m));
    y1 = min(HH - 1, (int)ceilf(fmaxf(g.p0y, g.p1y) + m));
}

__device__ __forceinline__ void strip_bbox(const Geom& g, float s0, float s1, float m,
                                           int& x0, int& x1, int& y0, int& y1) {
    float xmin = 1e9f, xmax = -1e9f, ymin = 1e9f, ymax = -1e9f;
    #pragma unroll
    for (int i = 0; i < 4; i++) {
        float s = (i & 1) ? s1 : s0;
        float r = (i & 2) ? m : -m;
        float x = g.p1x + s * g.ux - r * g.uy;
        float y = g.p1y + s * g.uy + r * g.ux;
        xmin = fminf(xmin, x); xmax = fmaxf(xmax, x);
        ymin = fminf(ymin, y); ymax = fmaxf(ymax, y);
    }
    x0 = max(0, (int)floorf(xmin)); x1 = min(WW - 1, (int)ceilf(xmax));
    y0 = max(0, (int)floorf(ymin)); y1 = min(HH - 1, (int)ceilf(ymax));
}

// 1024-thread block reduce, result broadcast to all threads; sm is float[16]
__device__ __forceinline__ float brb1024(float v, float* sm) {
    #pragma unroll
    for (int off = 32; off > 0; off >>= 1) v += __shfl_down(v, off);
    const int lane = threadIdx.x & 63, wid = threadIdx.x >> 6;
    if (lane == 0) sm[wid] = v;
    __syncthreads();
    float r = 0.f;
    #pragma unroll
    for (int i = 0; i < 16; i++) r += sm[i];
    __syncthreads();
    return r;
}

// ---- Kernel A: one block per image computes ALL three scalar reductions ----
// Stage 1: m_swept over capsule bbox (reads occ)
// Stage 2: existing over probe strip  (reads occ)
// Stage 3: summask over dep strip     (no loads)
// Writes sc[b*4 + {0,1,2}] = {pile, extra, dep_norm}
__global__ __launch_bounds__(1024)
void k_scalars(const float* __restrict__ occ, const float* __restrict__ as,
               const float* __restrict__ ae, float* __restrict__ sc) {
    const int b = blockIdx.x, tid = threadIdx.x;
    const int ty = tid >> 7, tx = tid & 127;        // 8 rows x 128 cols layout
    __shared__ float sm[16];
    Geom g = load_geom(as, ae, b);
    const float* base = occ + ((size_t)b << 20);

    int x0, x1, y0, y1;
    capsule_bbox(g, MARG, x0, x1, y0, y1);
    float sum = 0.f;
    for (int y = y0 + ty; y <= y1; y += 8) {
        const float fy = (float)y;
        for (int x = x0 + tx; x <= x1; x += 128)
            sum += base[((size_t)y << 10) + x] * sweptf(g, (float)x, fy);
    }
    const float m_swept = brb1024(sum, sm);
    const float pile = m_swept * (1.f / 6.f);

    strip_bbox(g, -MARG, pile + MARG, MARG, x0, x1, y0, y1);
    sum = 0.f;
    for (int y = y0 + ty; y <= y1; y += 8) {
        const float fy = (float)y;
        for (int x = x0 + tx; x <= x1; x += 128) {
            float s, lat; slat(g, (float)x, fy, s, lat);
            sum += base[((size_t)y << 10) + x] * sigf(s) * sigf(pile - s) * lat;
        }
    }
    const float existing = brb1024(sum, sm);
    const float extra = existing * (1.f / 6.f);

    strip_bbox(g, extra - MARG, extra + pile + MARG, MARG, x0, x1, y0, y1);
    sum = 0.f;
    for (int y = y0 + ty; y <= y1; y += 8) {
        const float fy = (float)y;
        for (int x = x0 + tx; x <= x1; x += 128) {
            float s, lat; slat(g, (float)x, fy, s, lat);
            sum += sigf(s - extra) * sigf(extra + pile - s) * lat;
        }
    }
    const float summask = brb1024(sum, sm);

    if (tid == 0) {
        sc[b * 4 + 0] = pile;
        sc[b * 4 + 1] = extra;
        sc[b * 4 + 2] = m_swept / (summask + EPSF);
    }
}

// ---- Kernel B: single full-image pass: out = occ*(1-swept) + blur(dep) -----
// Block (bx,b) owns rows [8*bx, 8*bx+8) x all 1024 cols. Thread t holds cols
// 4t..4t+3 of each of the 8 rows in registers (float4 v[8]). Blocks whose rows
// intersect the dep strip additionally build the analytic dep tile (16 halo
// rows x <=WMAX cols) in LDS, run the separable 9-tap blur, and add the result
// into the register values before the single coalesced store.
__global__ __launch_bounds__(256)
void k_fused(const float* __restrict__ occ, const float* __restrict__ as,
             const float* __restrict__ ae, const float* __restrict__ sc,
             float* __restrict__ out, BlurK wk) {
    const int b = blockIdx.y, bx = blockIdx.x, tid = threadIdx.x;
    const float pile     = sc[b * 4 + 0];
    const float extra    = sc[b * 4 + 1];
    const float dep_norm = sc[b * 4 + 2];
    Geom g = load_geom(as, ae, b);

    const size_t ibase = (size_t)b << 20;
    const float4* src = (const float4*)(occ + ibase);
    float4*       dst = (float4*)(out + ibase);
    const int yb = bx * 8;                  // first row of this block
    const int base4 = bx * 2048 + tid;      // + k*256 -> row yb+k, float4 col tid

    float4 v[8];
    #pragma unroll
    for (int k = 0; k < 8; k++) v[k] = src[base4 + k * 256];

    // occ * (1 - swept), only where swept is non-negligible
    int cx0, cx1, cy0, cy1; capsule_bbox(g, MARG, cx0, cx1, cy0, cy1);
    const int x = tid << 2;
    if (x + 3 >= cx0 && x <= cx1) {
        #pragma unroll
        for (int k = 0; k < 8; k++) {
            const int y = yb + k;
            if (y >= cy0 && y <= cy1) {
                const float fy = (float)y, fx = (float)x;
                v[k].x *= 1.f - sweptf(g, fx + 0.f, fy);
                v[k].y *= 1.f - sweptf(g, fx + 1.f, fy);
                v[k].z *= 1.f - sweptf(g, fx + 2.f, fy);
                v[k].w *= 1.f - sweptf(g, fx + 3.f, fy);
            }
        }
    }

    // blurred dep, only in blocks intersecting the dep strip rows
    int sx0, sx1, sy0, sy1;
    strip_bbox(g, extra - MARG, extra + pile + MARG, MARG, sx0, sx1, sy0, sy1);

    __shared__ float draw[16][FW];     // dep tile with 4-px halo (also reused for vb)
    __shared__ float hb[16][WMAX];     // horizontally blurred

    if (yb + 7 >= sy0 && yb <= sy1) {
        const int cxa = sx0 & ~3;      // 4-col aligned chunk start (for float4 adds)
        for (int cx = cxa; cx <= sx1; cx += WMAX) {
            const int w = min(WMAX, sx1 - cx + 1);   // valid output cols this chunk

            // analytic dep into draw: rows gy = yb-4+ly, cols gx = cx-4+lx
            for (int i = tid; i < 16 * FW; i += 256) {
                const int ly = i / FW, lx = i - ly * FW;   // FW const -> cheap div
                if (lx < w + 8) {
                    const int gy = yb - 4 + ly, gx = cx - 4 + lx;
                    float val = 0.f;
                    if ((unsigned)gx < WW && (unsigned)gy < HH) {
                        float s, lat; slat(g, (float)gx, (float)gy, s, lat);
                        val = sigf(s - extra) * sigf(extra + pile - s) * lat * dep_norm;
                    }
                    draw[ly][lx] = val;
                }
            }
            __syncthreads();

            // horizontal blur: 16 rows x w cols
            for (int i = tid; i < 16 * WMAX; i += 256) {
                const int ly = i >> 8, lx = i & 255;
                if (lx < w) {
                    float acc = 0.f;
                    #pragma unroll
                    for (int j = 0; j < 9; j++) acc += wk.k[j] * draw[ly][lx + j];
                    hb[ly][lx] = acc;
                }
            }
            __syncthreads();

            // vertical blur: 8 rows x w cols, written into draw rows 0..7 (free now)
            for (int i = tid; i < 8 * WMAX; i += 256) {
                const int k = i >> 8, lx = i & 255;
                if (lx < w) {
                    float acc = 0.f;
                    #pragma unroll
                    for (int j = 0; j < 9; j++) acc += wk.k[j] * hb[k + j][lx];
                    draw[k][lx] = acc;
                }
            }
            __syncthreads();

            // add blurred dep into this thread's register columns
            const int lx0 = (tid << 2) - cx;       // multiple of 4 (cx 4-aligned)
            if (lx0 >= 0 && lx0 < w) {
                if (lx0 + 3 < w) {
                    #pragma unroll
                    for (int k = 0; k < 8; k++) {
                        // row stride FW*4 = 1088 B (16B multiple), lx0 4-aligned
                        const float4 vb = *(const float4*)&draw[k][lx0];
                        v[k].x += vb.x; v[k].y += vb.y; v[k].z += vb.z; v[k].w += vb.w;
                    }
                } else {
                    #pragma unroll
                    for (int k = 0; k < 8; k++)
                        for (int e = 0; e < 4; e++)
                            if (lx0 + e < w) (&v[k].x)[e] += draw[k][lx0 + e];
                }
            }
            __syncthreads();   // before next chunk overwrites draw
        }
    }

    #pragma unroll
    for (int k = 0; k < 8; k++) dst[base4 + k * 256] = v[k];
}

extern "C" void kernel_launch(void* const* d_in, const int* in_sizes, int n_in,
                              void* d_out, int out_size, void* d_ws, size_t ws_size,
                              hipStream_t stream) {
    const float* occ = (const float*)d_in[0];
    const float* as  = (const float*)d_in[1];
    const float* ae  = (const float*)d_in[2];
    float* out = (float*)d_out;
    float* sc  = (float*)d_ws;            // BB*4 floats: {pile, extra, dep_norm, pad}

    BlurK wk;
    {
        float s = 0.f;
        for (int i = 0; i < 9; i++) {
            float t = (float)(i - RAD) / 1.5f;
            wk.k[i] = expf(-0.5f * t * t);
            s += wk.k[i];
        }
        for (int i = 0; i < 9; i++) wk.k[i] /= s;
    }

    k_scalars<<<dim3(BB), 1024, 0, stream>>>(occ, as, ae, sc);
    k_fused  <<<dim3(HH / 8, BB), 256, 0, stream>>>(occ, as, ae, sc, out, wk);
}

// Round 2
// 163.331 us; speedup vs baseline: 1.0224x; 1.0224x over previous
//
#include <hip/hip_runtime.h>
#include <math.h>

// Problem constants (B=16, H=W=1024, WIDTH=3, SIGMA=1, BLUR_SIGMA=1.5, EPS=1e-8)
#define BB    16
#define HH    1024
#define WW    1024
#define EPSF  1e-8f
#define RAD   4                  // blur radius: int(3 * 1.5)
#define MARG  24.f               // support margin: sigmoid(3-24) ~ 7.6e-10
#define WMAX  128                // max dep-chunk width per LDS pass
#define FW    (WMAX + 16)        // 144: draw row width
#define UNR   4                  // load-batch depth in k_scalars

struct BlurK { float k[9]; };

__device__ __forceinline__ float sigf(float z) {
    z = fmaxf(fminf(z, 40.f), -40.f);
    return 1.f / (1.f + __expf(-z));
}

struct Geom { float p0x, p0y, p1x, p1y, L, ux, uy; };

__device__ __forceinline__ Geom load_geom(const float* as, const float* ae, int b) {
    Geom g;
    g.p0x = as[3 * b];  g.p0y = as[3 * b + 1];
    g.p1x = ae[3 * b];  g.p1y = ae[3 * b + 1];
    float dx = g.p1x - g.p0x, dy = g.p1y - g.p0y;
    g.L  = sqrtf(dx * dx + dy * dy + EPSF);
    g.ux = dx / g.L;  g.uy = dy / g.L;
    return g;
}

__device__ __forceinline__ float sweptf(const Geom& g, float x, float y) {
    float rx = x - g.p0x, ry = y - g.p0y;
    float t  = fminf(fmaxf(rx * g.ux + ry * g.uy, 0.f), g.L);
    float dx = rx - t * g.ux, dy = ry - t * g.uy;
    float dist = sqrtf(dx * dx + dy * dy + EPSF);
    return sigf(3.f - dist);
}

__device__ __forceinline__ void slat(const Geom& g, float x, float y, float& s, float& lat) {
    float qx = x - g.p1x, qy = y - g.p1y;
    s = qx * g.ux + qy * g.uy;
    float r = qx * (-g.uy) + qy * g.ux;   // n = (-uy, ux)
    lat = sigf(3.f - fabsf(r));
}

__device__ __forceinline__ void capsule_bbox(const Geom& g, float m,
                                             int& x0, int& x1, int& y0, int& y1) {
    x0 = max(0, (int)floorf(fminf(g.p0x, g.p1x) - m));
    x1 = min(WW - 1, (int)ceilf(fmaxf(g.p0x, g.p1x) + m));
    y0 = max(0, (int)floorf(fminf(g.p0y, g.p1y) - m));
    y1 = min(HH - 1, (int)ceilf(fmaxf(g.p0y, g.p1y) + m));
}

__device__ __forceinline__ void strip_bbox(const Geom& g, float s0, float s1, float m,
                                           int& x0, int& x1, int& y0, int& y1) {
    float xmin = 1e9f, xmax = -1e9f, ymin = 1e9f, ymax = -1e9f;
    #pragma unroll
    for (int i = 0; i < 4; i++) {
        float s = (i & 1) ? s1 : s0;
        float r = (i & 2) ? m : -m;
        float x = g.p1x + s * g.ux - r * g.uy;
        float y = g.p1y + s * g.uy + r * g.ux;
        xmin = fminf(xmin, x); xmax = fmaxf(xmax, x);
        ymin = fminf(ymin, y); ymax = fmaxf(ymax, y);
    }
    x0 = max(0, (int)floorf(xmin)); x1 = min(WW - 1, (int)ceilf(xmax));
    y0 = max(0, (int)floorf(ymin)); y1 = min(HH - 1, (int)ceilf(ymax));
}

// constrain a*x ∈ [A,B]; returns false if empty. lo/hi updated.
__device__ __forceinline__ bool ivx(float a, float A, float B, float& lo, float& hi) {
    if (fabsf(a) < 1e-5f) return !(A > 0.f || B < 0.f);
    float l = A / a, h = B / a;
    if (a < 0.f) { float t = l; l = h; h = t; }
    lo = fmaxf(lo, l); hi = fminf(hi, h);
    return true;
}

// 1024-thread block reduce, result broadcast to all threads; sm is float[16]
__device__ __forceinline__ float brb1024(float v, float* sm) {
    #pragma unroll
    for (int off = 32; off > 0; off >>= 1) v += __shfl_down(v, off);
    const int lane = threadIdx.x & 63, wid = threadIdx.x >> 6;
    if (lane == 0) sm[wid] = v;
    __syncthreads();
    float r = 0.f;
    #pragma unroll
    for (int i = 0; i < 16; i++) r += sm[i];
    __syncthreads();
    return r;
}

// ---- Kernel A: one block per image computes ALL three scalar reductions ----
// float4 loads + 4-deep batches -> 16 pixels in flight per thread per latency.
// Widening bboxes to float4 alignment is exact (reference sums whole image).
__global__ __launch_bounds__(1024)
void k_scalars(const float* __restrict__ occ, const float* __restrict__ as,
               const float* __restrict__ ae, float* __restrict__ sc) {
    const int b = blockIdx.x, tid = threadIdx.x;
    const int tx4 = tid & 63;           // float4 column within a 64-f4 (256 px) window
    const int ty  = tid >> 6;           // 0..15, row stride 16
    __shared__ float sm[16];
    Geom g = load_geom(as, ae, b);
    const float4* src4 = (const float4*)(occ + ((size_t)b << 20));  // row y: [y*256 + c]

    int x0, x1, y0, y1;

    // ---- stage 1: m_swept over capsule bbox --------------------------------
    capsule_bbox(g, MARG, x0, x1, y0, y1);
    int c0 = x0 >> 2, c1 = x1 >> 2;
    float sum = 0.f;
    for (int cc = c0; cc <= c1; cc += 64) {
        const int c = cc + tx4;
        const bool cok = (c <= c1);
        const float fx = (float)(c << 2);
        for (int y = y0 + ty; y <= y1; y += 16 * UNR) {
            float4 vv[UNR];
            #pragma unroll
            for (int j = 0; j < UNR; j++) {
                const int yy = y + 16 * j;
                vv[j] = (cok && yy <= y1) ? src4[yy * 256 + c]
                                          : make_float4(0.f, 0.f, 0.f, 0.f);
            }
            #pragma unroll
            for (int j = 0; j < UNR; j++) {
                const int yy = y + 16 * j;
                if (cok && yy <= y1) {
                    const float fy = (float)yy;
                    sum += vv[j].x * sweptf(g, fx + 0.f, fy);
                    sum += vv[j].y * sweptf(g, fx + 1.f, fy);
                    sum += vv[j].z * sweptf(g, fx + 2.f, fy);
                    sum += vv[j].w * sweptf(g, fx + 3.f, fy);
                }
            }
        }
    }
    const float m_swept = brb1024(sum, sm);
    const float pile = m_swept * (1.f / 6.f);

    // ---- stage 2: existing over probe strip --------------------------------
    strip_bbox(g, -MARG, pile + MARG, MARG, x0, x1, y0, y1);
    c0 = x0 >> 2; c1 = x1 >> 2;
    sum = 0.f;
    for (int cc = c0; cc <= c1; cc += 64) {
        const int c = cc + tx4;
        const bool cok = (c <= c1);
        const float fx = (float)(c << 2);
        for (int y = y0 + ty; y <= y1; y += 16 * UNR) {
            float4 vv[UNR];
            #pragma unroll
            for (int j = 0; j < UNR; j++) {
                const int yy = y + 16 * j;
                vv[j] = (cok && yy <= y1) ? src4[yy * 256 + c]
                                          : make_float4(0.f, 0.f, 0.f, 0.f);
            }
            #pragma unroll
            for (int j = 0; j < UNR; j++) {
                const int yy = y + 16 * j;
                if (cok && yy <= y1) {
                    const float fy = (float)yy;
                    #pragma unroll
                    for (int e = 0; e < 4; e++) {
                        float s, lat; slat(g, fx + (float)e, fy, s, lat);
                        sum += (&vv[j].x)[e] * sigf(s) * sigf(pile - s) * lat;
                    }
                }
            }
        }
    }
    const float existing = brb1024(sum, sm);
    const float extra = existing * (1.f / 6.f);

    // ---- stage 3: summask over dep strip (no loads) ------------------------
    strip_bbox(g, extra - MARG, extra + pile + MARG, MARG, x0, x1, y0, y1);
    sum = 0.f;
    {
        const int tx = tid & 127, ty8 = tid >> 7;
        for (int y = y0 + ty8; y <= y1; y += 8) {
            const float fy = (float)y;
            for (int x = x0 + tx; x <= x1; x += 128) {
                float s, lat; slat(g, (float)x, fy, s, lat);
                sum += sigf(s - extra) * sigf(extra + pile - s) * lat;
            }
        }
    }
    const float summask = brb1024(sum, sm);

    if (tid == 0) {
        sc[b * 4 + 0] = pile;
        sc[b * 4 + 1] = extra;
        sc[b * 4 + 2] = m_swept / (summask + EPSF);
    }
}

// ---- Kernel B: single full-image pass: out = occ*(1-swept) + blur(dep) -----
__global__ __launch_bounds__(256)
void k_fused(const float* __restrict__ occ, const float* __restrict__ as,
             const float* __restrict__ ae, const float* __restrict__ sc,
             float* __restrict__ out, BlurK wk) {
    const int b = blockIdx.y, bx = blockIdx.x, tid = threadIdx.x;
    const float pile     = sc[b * 4 + 0];
    const float extra    = sc[b * 4 + 1];
    const float dep_norm = sc[b * 4 + 2];
    Geom g = load_geom(as, ae, b);

    const size_t ibase = (size_t)b << 20;
    const float4* src = (const float4*)(occ + ibase);
    float4*       dst = (float4*)(out + ibase);
    const int yb = bx * 8;                  // first row of this block
    const int base4 = bx * 2048 + tid;      // + k*256 -> row yb+k, float4 col tid

    float4 v[8];
    #pragma unroll
    for (int k = 0; k < 8; k++) v[k] = src[base4 + k * 256];

    // occ * (1 - swept), only where swept is non-negligible
    int cx0, cx1, cy0, cy1; capsule_bbox(g, MARG, cx0, cx1, cy0, cy1);
    const int x = tid << 2;
    if (x + 3 >= cx0 && x <= cx1) {
        #pragma unroll
        for (int k = 0; k < 8; k++) {
            const int y = yb + k;
            if (y >= cy0 && y <= cy1) {
                const float fy = (float)y, fx = (float)x;
                v[k].x *= 1.f - sweptf(g, fx + 0.f, fy);
                v[k].y *= 1.f - sweptf(g, fx + 1.f, fy);
                v[k].z *= 1.f - sweptf(g, fx + 2.f, fy);
                v[k].w *= 1.f - sweptf(g, fx + 3.f, fy);
            }
        }
    }

    // blurred dep, only in blocks intersecting the dep strip rows
    int sx0, sx1, sy0, sy1;
    strip_bbox(g, extra - MARG, extra + pile + MARG, MARG, sx0, sx1, sy0, sy1);

    __shared__ float draw[16][FW];     // dep tile with 4-px halo (rows 0..7 reused for vb)
    __shared__ float hb[16][WMAX];     // horizontally blurred

    if (yb + 7 >= sy0 && yb <= sy1) {
        // per-row-slab analytic x-clip of the rotated strip for rows [yb-4, yb+11]
        const float sA = extra - MARG, sB = extra + pile + MARG;
        float xlo = 1e9f, xhi = -1e9f;
        #pragma unroll
        for (int r = 0; r < 16; r++) {
            const float dy = (float)(yb - RAD + r) - g.p1y;
            float lo = -1e9f, hi = 1e9f;
            bool ok = ivx(g.ux, sA - dy * g.uy, sB - dy * g.uy, lo, hi);
            ok = ok && ivx(-g.uy, -MARG - dy * g.ux, MARG - dy * g.ux, lo, hi);
            if (ok && lo <= hi) { xlo = fminf(xlo, lo); xhi = fmaxf(xhi, hi); }
        }
        const int csx0 = max(sx0, (int)floorf(xlo + g.p1x));
        const int csx1 = min(sx1, (int)ceilf(xhi + g.p1x));

        if (csx0 <= csx1) {
            const int cxa = csx0 & ~3;     // 4-col aligned chunk start
            for (int cx = cxa; cx <= csx1; cx += WMAX) {
                const int w = min(WMAX, csx1 - cx + 1);

                // analytic dep into draw: rows gy = yb-4+ly, cols gx = cx-4+lx
                for (int i = tid; i < 16 * FW; i += 256) {
                    const int ly = i / FW, lx = i - ly * FW;
                    if (lx < w + 8) {
                        const int gy = yb - RAD + ly, gx = cx - RAD + lx;
                        float val = 0.f;
                        if ((unsigned)gx < WW && (unsigned)gy < HH) {
                            float s, lat; slat(g, (float)gx, (float)gy, s, lat);
                            val = sigf(s - extra) * sigf(extra + pile - s) * lat * dep_norm;
                        }
                        draw[ly][lx] = val;
                    }
                }
                __syncthreads();

                // horizontal blur: 16 rows x w cols
                for (int i = tid; i < 16 * WMAX; i += 256) {
                    const int ly = i >> 7, lx = i & 127;
                    if (lx < w) {
                        float acc = 0.f;
                        #pragma unroll
                        for (int j = 0; j < 9; j++) acc += wk.k[j] * draw[ly][lx + j];
                        hb[ly][lx] = acc;
                    }
                }
                __syncthreads();

                // vertical blur: 8 rows x w cols, into draw rows 0..7 (free now)
                for (int i = tid; i < 8 * WMAX; i += 256) {
                    const int k = i >> 7, lx = i & 127;
                    if (lx < w) {
                        float acc = 0.f;
                        #pragma unroll
                        for (int j = 0; j < 9; j++) acc += wk.k[j] * hb[k + j][lx];
                        draw[k][lx] = acc;
                    }
                }
                __syncthreads();

                // add blurred dep into this thread's register columns
                const int lx0 = (tid << 2) - cx;     // multiple of 4 (cx 4-aligned)
                if (lx0 >= 0 && lx0 < w) {
                    if (lx0 + 3 < w) {
                        #pragma unroll
                        for (int k = 0; k < 8; k++) {
                            const float4 vb = *(const float4*)&draw[k][lx0];
                            v[k].x += vb.x; v[k].y += vb.y; v[k].z += vb.z; v[k].w += vb.w;
                        }
                    } else {
                        #pragma unroll
                        for (int k = 0; k < 8; k++)
                            for (int e = 0; e < 4; e++)
                                if (lx0 + e < w) (&v[k].x)[e] += draw[k][lx0 + e];
                    }
                }
                __syncthreads();   // before next chunk overwrites draw
            }
        }
    }

    #pragma unroll
    for (int k = 0; k < 8; k++) dst[base4 + k * 256] = v[k];
}

extern "C" void kernel_launch(void* const* d_in, const int* in_sizes, int n_in,
                              void* d_out, int out_size, void* d_ws, size_t ws_size,
                              hipStream_t stream) {
    const float* occ = (const float*)d_in[0];
    const float* as  = (const float*)d_in[1];
    const float* ae  = (const float*)d_in[2];
    float* out = (float*)d_out;
    float* sc  = (float*)d_ws;            // BB*4 floats: {pile, extra, dep_norm, pad}

    BlurK wk;
    {
        float s = 0.f;
        for (int i = 0; i < 9; i++) {
            float t = (float)(i - RAD) / 1.5f;
            wk.k[i] = expf(-0.5f * t * t);
            s += wk.k[i];
        }
        for (int i = 0; i < 9; i++) wk.k[i] /= s;
    }

    k_scalars<<<dim3(BB), 1024, 0, stream>>>(occ, as, ae, sc);
    k_fused  <<<dim3(HH / 8, BB), 256, 0, stream>>>(occ, as, ae, sc, out, wk);
}

// Round 3
// 158.783 us; speedup vs baseline: 1.0517x; 1.0286x over previous
//
#include <hip/hip_runtime.h>
#include <math.h>

// Problem constants (B=16, H=W=1024, WIDTH=3, SIGMA=1, BLUR_SIGMA=1.5, EPS=1e-8)
#define BB    16
#define HH    1024
#define WW    1024
#define EPSF  1e-8f
#define RAD   4                  // blur radius: int(3 * 1.5)
#define MARG  24.f               // support margin: sigmoid(3-24) ~ 7.6e-10
#define NB1   128                // blocks per image in k_main (8 rows each)
#define NB3   32                 // blocks per image in k_dep
#define WMAX  128                // max dep-chunk width per LDS pass
#define FW    (WMAX + 16)        // 144: draw row width
#define UNR   4                  // load-batch depth in k_probe

struct BlurK { float k[9]; };

__device__ __forceinline__ float sigf(float z) {
    z = fmaxf(fminf(z, 40.f), -40.f);
    return 1.f / (1.f + __expf(-z));
}

struct Geom { float p0x, p0y, p1x, p1y, L, ux, uy; };

__device__ __forceinline__ Geom load_geom(const float* as, const float* ae, int b) {
    Geom g;
    g.p0x = as[3 * b];  g.p0y = as[3 * b + 1];
    g.p1x = ae[3 * b];  g.p1y = ae[3 * b + 1];
    float dx = g.p1x - g.p0x, dy = g.p1y - g.p0y;
    g.L  = sqrtf(dx * dx + dy * dy + EPSF);
    g.ux = dx / g.L;  g.uy = dy / g.L;
    return g;
}

__device__ __forceinline__ float sweptf(const Geom& g, float x, float y) {
    float rx = x - g.p0x, ry = y - g.p0y;
    float t  = fminf(fmaxf(rx * g.ux + ry * g.uy, 0.f), g.L);
    float dx = rx - t * g.ux, dy = ry - t * g.uy;
    float dist = sqrtf(dx * dx + dy * dy + EPSF);
    return sigf(3.f - dist);
}

__device__ __forceinline__ void slat(const Geom& g, float x, float y, float& s, float& lat) {
    float qx = x - g.p1x, qy = y - g.p1y;
    s = qx * g.ux + qy * g.uy;
    float r = qx * (-g.uy) + qy * g.ux;   // n = (-uy, ux)
    lat = sigf(3.f - fabsf(r));
}

__device__ __forceinline__ void capsule_bbox(const Geom& g, float m,
                                             int& x0, int& x1, int& y0, int& y1) {
    x0 = max(0, (int)floorf(fminf(g.p0x, g.p1x) - m));
    x1 = min(WW - 1, (int)ceilf(fmaxf(g.p0x, g.p1x) + m));
    y0 = max(0, (int)floorf(fminf(g.p0y, g.p1y) - m));
    y1 = min(HH - 1, (int)ceilf(fmaxf(g.p0y, g.p1y) + m));
}

__device__ __forceinline__ void strip_bbox(const Geom& g, float s0, float s1, float m,
                                           int& x0, int& x1, int& y0, int& y1) {
    float xmin = 1e9f, xmax = -1e9f, ymin = 1e9f, ymax = -1e9f;
    #pragma unroll
    for (int i = 0; i < 4; i++) {
        float s = (i & 1) ? s1 : s0;
        float r = (i & 2) ? m : -m;
        float x = g.p1x + s * g.ux - r * g.uy;
        float y = g.p1y + s * g.uy + r * g.ux;
        xmin = fminf(xmin, x); xmax = fmaxf(xmax, x);
        ymin = fminf(ymin, y); ymax = fmaxf(ymax, y);
    }
    x0 = max(0, (int)floorf(xmin)); x1 = min(WW - 1, (int)ceilf(xmax));
    y0 = max(0, (int)floorf(ymin)); y1 = min(HH - 1, (int)ceilf(ymax));
}

// constrain a*x ∈ [A,B]; returns false if empty. lo/hi updated.
__device__ __forceinline__ bool ivx(float a, float A, float B, float& lo, float& hi) {
    if (fabsf(a) < 1e-5f) return !(A > 0.f || B < 0.f);
    float l = A / a, h = B / a;
    if (a < 0.f) { float t = l; l = h; h = t; }
    lo = fmaxf(lo, l); hi = fminf(hi, h);
    return true;
}

// 256-thread block reduce, result broadcast; sm is float[4]
__device__ __forceinline__ float brb256(float v, float* sm) {
    #pragma unroll
    for (int off = 32; off > 0; off >>= 1) v += __shfl_down(v, off);
    const int lane = threadIdx.x & 63, wid = threadIdx.x >> 6;
    if (lane == 0) sm[wid] = v;
    __syncthreads();
    float r = sm[0] + sm[1] + sm[2] + sm[3];
    __syncthreads();
    return r;
}

// 1024-thread block reduce, result broadcast; sm is float[16]
__device__ __forceinline__ float brb1024(float v, float* sm) {
    #pragma unroll
    for (int off = 32; off > 0; off >>= 1) v += __shfl_down(v, off);
    const int lane = threadIdx.x & 63, wid = threadIdx.x >> 6;
    if (lane == 0) sm[wid] = v;
    __syncthreads();
    float r = 0.f;
    #pragma unroll
    for (int i = 0; i < 16; i++) r += sm[i];
    __syncthreads();
    return r;
}

// ---- K1: FIRST kernel. Full-image stream: out = occ*(1-swept), fused with
// m_swept block partials. 2048 blocks -> absorbs the post-poison-fill L3/HBM
// drain with sheer parallelism and warms occ into L3 for k_probe.
__global__ __launch_bounds__(256)
void k_main(const float* __restrict__ occ, const float* __restrict__ as,
            const float* __restrict__ ae, float* __restrict__ out,
            float* __restrict__ part1) {
    const int b = blockIdx.y, bx = blockIdx.x, tid = threadIdx.x;
    Geom g = load_geom(as, ae, b);
    const size_t ibase = (size_t)b << 20;
    const float4* src = (const float4*)(occ + ibase);
    float4*       dst = (float4*)(out + ibase);
    const int yb = bx * 8;                  // first row of this block
    const int base4 = bx * 2048 + tid;      // + k*256 -> row yb+k, float4 col tid

    float4 v[8];
    #pragma unroll
    for (int k = 0; k < 8; k++) v[k] = src[base4 + k * 256];

    int cx0, cx1, cy0, cy1; capsule_bbox(g, MARG, cx0, cx1, cy0, cy1);
    const int x = tid << 2;
    float msum = 0.f;
    if (x + 3 >= cx0 && x <= cx1) {
        #pragma unroll
        for (int k = 0; k < 8; k++) {
            const int y = yb + k;
            if (y >= cy0 && y <= cy1) {
                const float fy = (float)y, fx = (float)x;
                const float s0 = sweptf(g, fx + 0.f, fy);
                const float s1 = sweptf(g, fx + 1.f, fy);
                const float s2 = sweptf(g, fx + 2.f, fy);
                const float s3 = sweptf(g, fx + 3.f, fy);
                msum += v[k].x * s0 + v[k].y * s1 + v[k].z * s2 + v[k].w * s3;
                v[k].x *= 1.f - s0; v[k].y *= 1.f - s1;
                v[k].z *= 1.f - s2; v[k].w *= 1.f - s3;
            }
        }
    }
    #pragma unroll
    for (int k = 0; k < 8; k++) dst[base4 + k * 256] = v[k];

    __shared__ float sm[4];
    const float bs = brb256(msum, sm);
    if (tid == 0) part1[b * NB1 + bx] = bs;
}

// ---- K2: per-image scalar chain on L3-warm data --------------------------
// reduce m_swept partials -> pile; existing over probe strip (occ reads now
// L3 hits); summask over dep strip (VALU only); write {pile, extra, dep_norm}
__global__ __launch_bounds__(1024)
void k_probe(const float* __restrict__ occ, const float* __restrict__ as,
             const float* __restrict__ ae, const float* __restrict__ part1,
             float* __restrict__ sc) {
    const int b = blockIdx.x, tid = threadIdx.x;
    const int tx4 = tid & 63;           // float4 column within a 64-f4 window
    const int ty  = tid >> 6;           // 0..15, row stride 16
    __shared__ float sm[16];
    Geom g = load_geom(as, ae, b);
    const float4* src4 = (const float4*)(occ + ((size_t)b << 20));

    const float m_swept = brb1024((tid < NB1) ? part1[b * NB1 + tid] : 0.f, sm);
    const float pile = m_swept * (1.f / 6.f);

    // ---- existing over probe strip (float4 + 4-deep batches) --------------
    int x0, x1, y0, y1;
    strip_bbox(g, -MARG, pile + MARG, MARG, x0, x1, y0, y1);
    int c0 = x0 >> 2, c1 = x1 >> 2;
    float sum = 0.f;
    for (int cc = c0; cc <= c1; cc += 64) {
        const int c = cc + tx4;
        const bool cok = (c <= c1);
        const float fx = (float)(c << 2);
        for (int y = y0 + ty; y <= y1; y += 16 * UNR) {
            float4 vv[UNR];
            #pragma unroll
            for (int j = 0; j < UNR; j++) {
                const int yy = y + 16 * j;
                vv[j] = (cok && yy <= y1) ? src4[yy * 256 + c]
                                          : make_float4(0.f, 0.f, 0.f, 0.f);
            }
            #pragma unroll
            for (int j = 0; j < UNR; j++) {
                const int yy = y + 16 * j;
                if (cok && yy <= y1) {
                    const float fy = (float)yy;
                    #pragma unroll
                    for (int e = 0; e < 4; e++) {
                        float s, lat; slat(g, fx + (float)e, fy, s, lat);
                        sum += (&vv[j].x)[e] * sigf(s) * sigf(pile - s) * lat;
                    }
                }
            }
        }
    }
    const float existing = brb1024(sum, sm);
    const float extra = existing * (1.f / 6.f);

    // ---- summask over dep strip (no loads) --------------------------------
    strip_bbox(g, extra - MARG, extra + pile + MARG, MARG, x0, x1, y0, y1);
    sum = 0.f;
    {
        const int tx = tid & 127, ty8 = tid >> 7;
        for (int y = y0 + ty8; y <= y1; y += 8) {
            const float fy = (float)y;
            for (int x = x0 + tx; x <= x1; x += 128) {
                float s, lat; slat(g, (float)x, fy, s, lat);
                sum += sigf(s - extra) * sigf(extra + pile - s) * lat;
            }
        }
    }
    const float summask = brb1024(sum, sm);

    if (tid == 0) {
        sc[b * 4 + 0] = pile;
        sc[b * 4 + 1] = extra;
        sc[b * 4 + 2] = m_swept / (summask + EPSF);
    }
}

// ---- K3: dep strip only: out += blur(dep), LDS separable blur ------------
// 8-row slabs over the strip bbox, per-slab analytic x-clip, chunks of WMAX.
// Slabs/chunks tile the strip disjointly -> plain RMW, no atomics.
__global__ __launch_bounds__(256)
void k_dep(const float* __restrict__ as, const float* __restrict__ ae,
           const float* __restrict__ sc, float* __restrict__ out, BlurK wk) {
    const int b = blockIdx.y, bx = blockIdx.x, tid = threadIdx.x;
    const float pile     = sc[b * 4 + 0];
    const float extra    = sc[b * 4 + 1];
    const float dep_norm = sc[b * 4 + 2];
    Geom g = load_geom(as, ae, b);

    int sx0, sx1, sy0, sy1;
    strip_bbox(g, extra - MARG, extra + pile + MARG, MARG, sx0, sx1, sy0, sy1);
    if (sx0 > sx1 || sy0 > sy1) return;
    float* outb = out + ((size_t)b << 20);

    __shared__ float draw[16][FW];     // dep tile with 4-px halo (rows 0..7 reused)
    __shared__ float hb[16][WMAX];     // horizontally blurred

    const int nty = (sy1 - sy0) / 8 + 1;
    const float sA = extra - MARG, sB = extra + pile + MARG;

    for (int ty = bx; ty < nty; ty += NB3) {
        const int yt = sy0 + ty * 8;

        // per-row-slab analytic x-clip of the rotated strip, rows [yt-4, yt+11]
        float xlo = 1e9f, xhi = -1e9f;
        #pragma unroll
        for (int r = 0; r < 16; r++) {
            const float dy = (float)(yt - RAD + r) - g.p1y;
            float lo = -1e9f, hi = 1e9f;
            bool ok = ivx(g.ux, sA - dy * g.uy, sB - dy * g.uy, lo, hi);
            ok = ok && ivx(-g.uy, -MARG - dy * g.ux, MARG - dy * g.ux, lo, hi);
            if (ok && lo <= hi) { xlo = fminf(xlo, lo); xhi = fmaxf(xhi, hi); }
        }
        const int csx0 = max(sx0, (int)floorf(xlo + g.p1x));
        const int csx1 = min(sx1, (int)ceilf(xhi + g.p1x));
        if (csx0 > csx1) continue;

        for (int cx = csx0 & ~3; cx <= csx1; cx += WMAX) {
            const int w = min(WMAX, csx1 - cx + 1);

            // analytic dep into draw: rows gy = yt-4+ly, cols gx = cx-4+lx
            for (int i = tid; i < 16 * FW; i += 256) {
                const int ly = i / FW, lx = i - ly * FW;
                if (lx < w + 8) {
                    const int gy = yt - RAD + ly, gx = cx - RAD + lx;
                    float val = 0.f;
                    if ((unsigned)gx < WW && (unsigned)gy < HH) {
                        float s, lat; slat(g, (float)gx, (float)gy, s, lat);
                        val = sigf(s - extra) * sigf(extra + pile - s) * lat * dep_norm;
                    }
                    draw[ly][lx] = val;
                }
            }
            __syncthreads();

            // horizontal blur: 16 rows x w cols
            for (int i = tid; i < 16 * WMAX; i += 256) {
                const int ly = i >> 7, lx = i & 127;
                if (lx < w) {
                    float acc = 0.f;
                    #pragma unroll
                    for (int j = 0; j < 9; j++) acc += wk.k[j] * draw[ly][lx + j];
                    hb[ly][lx] = acc;
                }
            }
            __syncthreads();

            // vertical blur: 8 rows x w cols, into draw rows 0..7 (free now)
            for (int i = tid; i < 8 * WMAX; i += 256) {
                const int k = i >> 7, lx = i & 127;
                if (lx < w) {
                    float acc = 0.f;
                    #pragma unroll
                    for (int j = 0; j < 9; j++) acc += wk.k[j] * hb[k + j][lx];
                    draw[k][lx] = acc;
                }
            }
            __syncthreads();

            // apply: out[yt+k][cx+lx] += blurred dep (disjoint tiles, no atomics)
            for (int i = tid; i < 8 * WMAX; i += 256) {
                const int k = i >> 7, lx = i & 127;
                const int gy = yt + k, gx = cx + lx;
                if (lx < w && (unsigned)gy < HH && (unsigned)gx < WW)
                    outb[((size_t)gy << 10) + gx] += draw[k][lx];
            }
            __syncthreads();   // before next chunk overwrites draw
        }
    }
}

extern "C" void kernel_launch(void* const* d_in, const int* in_sizes, int n_in,
                              void* d_out, int out_size, void* d_ws, size_t ws_size,
                              hipStream_t stream) {
    const float* occ = (const float*)d_in[0];
    const float* as  = (const float*)d_in[1];
    const float* ae  = (const float*)d_in[2];
    float* out   = (float*)d_out;
    float* part1 = (float*)d_ws;                 // BB*NB1 floats
    float* sc    = part1 + BB * NB1;             // BB*4: {pile, extra, dep_norm, pad}

    BlurK wk;
    {
        float s = 0.f;
        for (int i = 0; i < 9; i++) {
            float t = (float)(i - RAD) / 1.5f;
            wk.k[i] = expf(-0.5f * t * t);
            s += wk.k[i];
        }
        for (int i = 0; i < 9; i++) wk.k[i] /= s;
    }

    k_main <<<dim3(NB1, BB), 256,  0, stream>>>(occ, as, ae, out, part1);
    k_probe<<<dim3(BB),      1024, 0, stream>>>(occ, as, ae, part1, sc);
    k_dep  <<<dim3(NB3, BB), 256,  0, stream>>>(as, ae, sc, out, wk);
}

// Round 5
// 135.601 us; speedup vs baseline: 1.2315x; 1.1710x over previous
//
#include <hip/hip_runtime.h>
#include <math.h>

// Problem constants (B=16, H=W=1024, WIDTH=3, SIGMA=1, BLUR_SIGMA=1.5, EPS=1e-8)
#define BB    16
#define HH    1024
#define WW    1024
#define EPSF  1e-8f
#define RAD   4                  // blur radius: int(3 * 1.5)
#define MARG  24.f               // support margin: sigmoid(3-24) ~ 7.6e-10
#define NB1   128                // blocks per image in k_main (8 rows each)
#define NB2   64                 // blocks per image in k_existing / k_summask
#define NB3   32                 // blocks per image in k_dep
#define WMAX  128                // max dep-chunk width per LDS pass
#define FW    (WMAX + 16)        // 144: draw row width

struct BlurK { float k[9]; };

__device__ __forceinline__ float sigf(float z) {
    z = fmaxf(fminf(z, 40.f), -40.f);
    return 1.f / (1.f + __expf(-z));
}

struct Geom { float p0x, p0y, p1x, p1y, L, ux, uy; };

__device__ __forceinline__ Geom load_geom(const float* as, const float* ae, int b) {
    Geom g;
    g.p0x = as[3 * b];  g.p0y = as[3 * b + 1];
    g.p1x = ae[3 * b];  g.p1y = ae[3 * b + 1];
    float dx = g.p1x - g.p0x, dy = g.p1y - g.p0y;
    g.L  = sqrtf(dx * dx + dy * dy + EPSF);
    g.ux = dx / g.L;  g.uy = dy / g.L;
    return g;
}

__device__ __forceinline__ float sweptf(const Geom& g, float x, float y) {
    float rx = x - g.p0x, ry = y - g.p0y;
    float t  = fminf(fmaxf(rx * g.ux + ry * g.uy, 0.f), g.L);
    float dx = rx - t * g.ux, dy = ry - t * g.uy;
    float dist = sqrtf(dx * dx + dy * dy + EPSF);
    return sigf(3.f - dist);
}

__device__ __forceinline__ void slat(const Geom& g, float x, float y, float& s, float& lat) {
    float qx = x - g.p1x, qy = y - g.p1y;
    s = qx * g.ux + qy * g.uy;
    float r = qx * (-g.uy) + qy * g.ux;   // n = (-uy, ux)
    lat = sigf(3.f - fabsf(r));
}

__device__ __forceinline__ void capsule_bbox(const Geom& g, float m,
                                             int& x0, int& x1, int& y0, int& y1) {
    x0 = max(0, (int)floorf(fminf(g.p0x, g.p1x) - m));
    x1 = min(WW - 1, (int)ceilf(fmaxf(g.p0x, g.p1x) + m));
    y0 = max(0, (int)floorf(fminf(g.p0y, g.p1y) - m));
    y1 = min(HH - 1, (int)ceilf(fmaxf(g.p0y, g.p1y) + m));
}

__device__ __forceinline__ void strip_bbox(const Geom& g, float s0, float s1, float m,
                                           int& x0, int& x1, int& y0, int& y1) {
    float xmin = 1e9f, xmax = -1e9f, ymin = 1e9f, ymax = -1e9f;
    #pragma unroll
    for (int i = 0; i < 4; i++) {
        float s = (i & 1) ? s1 : s0;
        float r = (i & 2) ? m : -m;
        float x = g.p1x + s * g.ux - r * g.uy;
        float y = g.p1y + s * g.uy + r * g.ux;
        xmin = fminf(xmin, x); xmax = fmaxf(xmax, x);
        ymin = fminf(ymin, y); ymax = fmaxf(ymax, y);
    }
    x0 = max(0, (int)floorf(xmin)); x1 = min(WW - 1, (int)ceilf(xmax));
    y0 = max(0, (int)floorf(ymin)); y1 = min(HH - 1, (int)ceilf(ymax));
}

// constrain a*x ∈ [A,B]; returns false if empty. lo/hi updated.
__device__ __forceinline__ bool ivx(float a, float A, float B, float& lo, float& hi) {
    if (fabsf(a) < 1e-5f) return !(A > 0.f || B < 0.f);
    float l = A / a, h = B / a;
    if (a < 0.f) { float t = l; l = h; h = t; }
    lo = fmaxf(lo, l); hi = fminf(hi, h);
    return true;
}

// 256-thread block reduce, result broadcast; sm is float[4]
__device__ __forceinline__ float brb256(float v, float* sm) {
    #pragma unroll
    for (int off = 32; off > 0; off >>= 1) v += __shfl_down(v, off);
    const int lane = threadIdx.x & 63, wid = threadIdx.x >> 6;
    if (lane == 0) sm[wid] = v;
    __syncthreads();
    float r = sm[0] + sm[1] + sm[2] + sm[3];
    __syncthreads();
    return r;
}

// ---- K1: full-image stream: out = occ*(1-swept), fused m_swept partials ----
// 2048 blocks: wide enough to ride out the concurrent harness fill traffic.
__global__ __launch_bounds__(256)
void k_main(const float* __restrict__ occ, const float* __restrict__ as,
            const float* __restrict__ ae, float* __restrict__ out,
            float* __restrict__ part1) {
    const int b = blockIdx.y, bx = blockIdx.x, tid = threadIdx.x;
    Geom g = load_geom(as, ae, b);
    const size_t ibase = (size_t)b << 20;
    const float4* src = (const float4*)(occ + ibase);
    float4*       dst = (float4*)(out + ibase);
    const int yb = bx * 8;                  // first row of this block
    const int base4 = bx * 2048 + tid;      // + k*256 -> row yb+k, float4 col tid

    float4 v[8];
    #pragma unroll
    for (int k = 0; k < 8; k++) v[k] = src[base4 + k * 256];

    int cx0, cx1, cy0, cy1; capsule_bbox(g, MARG, cx0, cx1, cy0, cy1);
    const int x = tid << 2;
    float msum = 0.f;
    if (x + 3 >= cx0 && x <= cx1) {
        #pragma unroll
        for (int k = 0; k < 8; k++) {
            const int y = yb + k;
            if (y >= cy0 && y <= cy1) {
                const float fy = (float)y, fx = (float)x;
                const float s0 = sweptf(g, fx + 0.f, fy);
                const float s1 = sweptf(g, fx + 1.f, fy);
                const float s2 = sweptf(g, fx + 2.f, fy);
                const float s3 = sweptf(g, fx + 3.f, fy);
                msum += v[k].x * s0 + v[k].y * s1 + v[k].z * s2 + v[k].w * s3;
                v[k].x *= 1.f - s0; v[k].y *= 1.f - s1;
                v[k].z *= 1.f - s2; v[k].w *= 1.f - s3;
            }
        }
    }
    #pragma unroll
    for (int k = 0; k < 8; k++) dst[base4 + k * 256] = v[k];

    __shared__ float sm[4];
    const float bs = brb256(msum, sm);
    if (tid == 0) part1[b * NB1 + bx] = bs;
}

// ---- K2: existing partials over probe strip bbox (wide grid, L3-warm) ------
__global__ __launch_bounds__(256)
void k_existing(const float* __restrict__ occ, const float* __restrict__ as,
                const float* __restrict__ ae, const float* __restrict__ part1,
                float* __restrict__ part2) {
    const int b = blockIdx.y, bx = blockIdx.x, tid = threadIdx.x;
    __shared__ float sm[4];
    const float m_swept = brb256((tid < NB1) ? part1[b * NB1 + tid] : 0.f, sm);
    const float pile = m_swept * (1.f / 6.f);

    Geom g = load_geom(as, ae, b);
    int x0, x1, y0, y1; strip_bbox(g, -MARG, pile + MARG, MARG, x0, x1, y0, y1);
    const float* base = occ + ((size_t)b << 20);
    float sum = 0.f;
    for (int y = y0 + bx; y <= y1; y += NB2) {
        const float fy = (float)y;
        for (int x = x0 + tid; x <= x1; x += 256) {
            float s, lat; slat(g, (float)x, fy, s, lat);
            sum += base[((size_t)y << 10) + x] * sigf(s) * sigf(pile - s) * lat;
        }
    }
    const float bs = brb256(sum, sm);
    if (tid == 0) part2[b * NB2 + bx] = bs;
}

// ---- K3: summask partials over dep strip bbox (no loads) -------------------
__global__ __launch_bounds__(256)
void k_summask(const float* __restrict__ as, const float* __restrict__ ae,
               const float* __restrict__ part1, const float* __restrict__ part2,
               float* __restrict__ part3) {
    const int b = blockIdx.y, bx = blockIdx.x, tid = threadIdx.x;
    __shared__ float sm[4];
    const float m_swept  = brb256((tid < NB1) ? part1[b * NB1 + tid] : 0.f, sm);
    const float existing = brb256((tid < NB2) ? part2[b * NB2 + tid] : 0.f, sm);
    const float pile  = m_swept * (1.f / 6.f);
    const float extra = existing * (1.f / 6.f);

    Geom g = load_geom(as, ae, b);
    int x0, x1, y0, y1;
    strip_bbox(g, extra - MARG, extra + pile + MARG, MARG, x0, x1, y0, y1);
    float sum = 0.f;
    for (int y = y0 + bx; y <= y1; y += NB2) {
        const float fy = (float)y;
        for (int x = x0 + tid; x <= x1; x += 256) {
            float s, lat; slat(g, (float)x, fy, s, lat);
            sum += sigf(s - extra) * sigf(extra + pile - s) * lat;
        }
    }
    const float bs = brb256(sum, sm);
    if (tid == 0) part3[b * NB2 + bx] = bs;
}

// ---- K4: dep strip only: out += blur(dep), LDS separable blur --------------
// 8-row slabs over the strip bbox, per-slab analytic x-clip, WMAX chunks.
// Slabs/chunks tile the strip disjointly -> plain RMW, no atomics. Coherent
// with K1's stores via inter-kernel (same-stream) ordering.
__global__ __launch_bounds__(256)
void k_dep(const float* __restrict__ as, const float* __restrict__ ae,
           const float* __restrict__ part1, const float* __restrict__ part2,
           const float* __restrict__ part3, float* __restrict__ out, BlurK wk) {
    const int b = blockIdx.y, bx = blockIdx.x, tid = threadIdx.x;
    __shared__ float sm[4];
    const float m_swept  = brb256((tid < NB1) ? part1[b * NB1 + tid] : 0.f, sm);
    const float existing = brb256((tid < NB2) ? part2[b * NB2 + tid] : 0.f, sm);
    const float summask  = brb256((tid < NB2) ? part3[b * NB2 + tid] : 0.f, sm);
    const float pile     = m_swept * (1.f / 6.f);
    const float extra    = existing * (1.f / 6.f);
    const float dep_norm = m_swept / (summask + EPSF);

    Geom g = load_geom(as, ae, b);
    int sx0, sx1, sy0, sy1;
    strip_bbox(g, extra - MARG, extra + pile + MARG, MARG, sx0, sx1, sy0, sy1);
    if (sx0 > sx1 || sy0 > sy1) return;
    float* outb = out + ((size_t)b << 20);

    __shared__ float draw[16][FW];     // dep tile with 4-px halo (rows 0..7 reused)
    __shared__ float hb[16][WMAX];     // horizontally blurred

    const int nty = (sy1 - sy0) / 8 + 1;
    const float sA = extra - MARG, sB = extra + pile + MARG;

    for (int ty = bx; ty < nty; ty += NB3) {
        const int yt = sy0 + ty * 8;

        // per-row-slab analytic x-clip of the rotated strip, rows [yt-4, yt+11]
        float xlo = 1e9f, xhi = -1e9f;
        #pragma unroll
        for (int r = 0; r < 16; r++) {
            const float dy = (float)(yt - RAD + r) - g.p1y;
            float lo = -1e9f, hi = 1e9f;
            bool ok = ivx(g.ux, sA - dy * g.uy, sB - dy * g.uy, lo, hi);
            ok = ok && ivx(-g.uy, -MARG - dy * g.ux, MARG - dy * g.ux, lo, hi);
            if (ok && lo <= hi) { xlo = fminf(xlo, lo); xhi = fmaxf(xhi, hi); }
        }
        const int csx0 = max(sx0, (int)floorf(xlo + g.p1x));
        const int csx1 = min(sx1, (int)ceilf(xhi + g.p1x));
        if (csx0 > csx1) continue;

        for (int cx = csx0 & ~3; cx <= csx1; cx += WMAX) {
            const int w = min(WMAX, csx1 - cx + 1);

            // analytic dep into draw: rows gy = yt-4+ly, cols gx = cx-4+lx
            for (int i = tid; i < 16 * FW; i += 256) {
                const int ly = i / FW, lx = i - ly * FW;
                if (lx < w + 8) {
                    const int gy = yt - RAD + ly, gx = cx - RAD + lx;
                    float val = 0.f;
                    if ((unsigned)gx < WW && (unsigned)gy < HH) {
                        float s, lat; slat(g, (float)gx, (float)gy, s, lat);
                        val = sigf(s - extra) * sigf(extra + pile - s) * lat * dep_norm;
                    }
                    draw[ly][lx] = val;
                }
            }
            __syncthreads();

            // horizontal blur: 16 rows x w cols
            for (int i = tid; i < 16 * WMAX; i += 256) {
                const int ly = i >> 7, lx = i & 127;
                if (lx < w) {
                    float acc = 0.f;
                    #pragma unroll
                    for (int j = 0; j < 9; j++) acc += wk.k[j] * draw[ly][lx + j];
                    hb[ly][lx] = acc;
                }
            }
            __syncthreads();

            // vertical blur: 8 rows x w cols, into draw rows 0..7 (free now)
            for (int i = tid; i < 8 * WMAX; i += 256) {
                const int k = i >> 7, lx = i & 127;
                if (lx < w) {
                    float acc = 0.f;
                    #pragma unroll
                    for (int j = 0; j < 9; j++) acc += wk.k[j] * hb[k + j][lx];
                    draw[k][lx] = acc;
                }
            }
            __syncthreads();

            // apply: out[yt+k][cx+lx] += blurred dep (disjoint tiles)
            for (int i = tid; i < 8 * WMAX; i += 256) {
                const int k = i >> 7, lx = i & 127;
                const int gy = yt + k, gx = cx + lx;
                if (lx < w && (unsigned)gy < HH && (unsigned)gx < WW)
                    outb[((size_t)gy << 10) + gx] += draw[k][lx];
            }
            __syncthreads();   // before next chunk overwrites draw
        }
    }
}

extern "C" void kernel_launch(void* const* d_in, const int* in_sizes, int n_in,
                              void* d_out, int out_size, void* d_ws, size_t ws_size,
                              hipStream_t stream) {
    const float* occ = (const float*)d_in[0];
    const float* as  = (const float*)d_in[1];
    const float* ae  = (const float*)d_in[2];
    float* out   = (float*)d_out;
    float* part1 = (float*)d_ws;                 // BB*NB1 floats
    float* part2 = part1 + BB * NB1;             // BB*NB2 floats
    float* part3 = part2 + BB * NB2;             // BB*NB2 floats

    BlurK wk;
    {
        float s = 0.f;
        for (int i = 0; i < 9; i++) {
            float t = (float)(i - RAD) / 1.5f;
            wk.k[i] = expf(-0.5f * t * t);
            s += wk.k[i];
        }
        for (int i = 0; i < 9; i++) wk.k[i] /= s;
    }

    k_main    <<<dim3(NB1, BB), 256, 0, stream>>>(occ, as, ae, out, part1);
    k_existing<<<dim3(NB2, BB), 256, 0, stream>>>(occ, as, ae, part1, part2);
    k_summask <<<dim3(NB2, BB), 256, 0, stream>>>(as, ae, part1, part2, part3);
    k_dep     <<<dim3(NB3, BB), 256, 0, stream>>>(as, ae, part1, part2, part3, out, wk);
}